// Round 12
// baseline (365.771 us; speedup 1.0000x reference)
//
#include <hip/hip_runtime.h>
#include <stdint.h>

// ---------------------------------------------------------------------------
// GraphSAGE 2-layer: out = SAGE2(relu(SAGE1(x)))
// SAGE(x) = mean_agg(x@W_l.T) + b + x@W_r.T   (project-then-aggregate rewrite)
// R18: R16 (362us best) with gemm K-step doubled: BK=64 -> 12 bodies, HALF
// the barriers+waits (the only remaining per-body cost after R15 ruled out
// pipeline depth and R17 ruled out TLP). LDS 64KB -> 2 blocks/CU = the
// existing VGPR-bin residency (free, unlike m132's BK=128). A staged
// [128][64] row-major with XOR chunk-swizzle (linear LDS dest + inverse-
// swizzled GLOBAL source + swizzled read; involution verified) -> balanced
// banks + 128B-coalesced staging. B map extended with the k-half bit
// (reduces to the R12-proven map per half). Steady vmcnt(4), tail 0.
// ---------------------------------------------------------------------------

#define D_IN  768
#define D_HID 256
#define N1    512   // concat(W1_l, W1_r) output width
#define KBODY 12    // K bodies at BK=64 (768/64)

typedef __attribute__((ext_vector_type(8))) short short8;
typedef __attribute__((ext_vector_type(4))) float f32x4;

__device__ __forceinline__ void async_copy16(const void* g, void* l) {
  __builtin_amdgcn_global_load_lds(
      (const __attribute__((address_space(1))) unsigned int*)g,
      (__attribute__((address_space(3))) unsigned int*)l,
      16, 0, 0);
}

__device__ __forceinline__ unsigned short f2bf(float f) {
  union { float f; unsigned u; } v; v.f = f;
  unsigned r = v.u + 0x7FFFu + ((v.u >> 16) & 1u);   // RNE
  return (unsigned short)(r >> 16);
}

__device__ __forceinline__ float bf2f(unsigned short b) {
  union { unsigned u; float f; } v; v.u = ((unsigned)b) << 16;
  return v.f;
}

// ------------------- fused prep: cvtidx | cvtw | cvtx ----------------------
// Three independent streaming jobs in one launch, selected by block range:
//   [0, gE)            edge-index convert + degree count
//   [gE, gE+gW)        W1 -> bf16 wb
//   [gE+gW, gE+gW+gX)  x -> bf16 xb (padded to Mp rows)
__global__ void prep_k(const void* __restrict__ eidx,
                       int* __restrict__ src32, int* __restrict__ dst32,
                       int* __restrict__ counts, int E,
                       const float* __restrict__ W1l, const float* __restrict__ W1r,
                       unsigned short* __restrict__ wb,
                       const float* __restrict__ x,
                       unsigned short* __restrict__ xb, int M, int Mp,
                       int gE, int gW) {
  const int tid = threadIdx.x;
  const int bid = blockIdx.x;

  if (bid < gE) {
    // cvtidx: block-local int64/int32 detection (int64 LE: odd words 0)
    __shared__ int flag32;
    int i = bid * 256 + tid;
    unsigned v = (i < E) ? ((const unsigned int*)eidx)[2 * (size_t)i + 1] : 0u;
    unsigned long long any = __ballot(v != 0u);
    if (tid == 0) flag32 = 0;
    __syncthreads();
    if ((tid & 63) == 0 && any) flag32 = 1;  // benign multi-writer
    __syncthreads();
    if (i >= E) return;
    int s, d;
    if (flag32) {
      const int* p = (const int*)eidx;
      s = p[i]; d = p[E + i];
    } else {
      const long long* p = (const long long*)eidx;
      s = (int)p[i]; d = (int)p[E + i];
    }
    src32[i] = s;
    dst32[i] = d;
    atomicAdd(&counts[d], 1);
    return;
  }

  if (bid < gE + gW) {
    // cvtw: wb rows 0..255 = W1_l, 256..511 = W1_r (each [256,768])
    int idx = (bid - gE) * 256 + tid;
    int total = N1 * (D_IN / 8);
    if (idx >= total) return;
    int row = idx / (D_IN / 8);
    int cpos = (idx % (D_IN / 8)) * 8;
    const float* p = (row < D_HID) ? (W1l + (size_t)row * D_IN + cpos)
                                   : (W1r + (size_t)(row - D_HID) * D_IN + cpos);
    float4 f0 = *(const float4*)p;
    float4 f1 = *(const float4*)(p + 4);
    short8 o;
    o[0] = (short)f2bf(f0.x); o[1] = (short)f2bf(f0.y);
    o[2] = (short)f2bf(f0.z); o[3] = (short)f2bf(f0.w);
    o[4] = (short)f2bf(f1.x); o[5] = (short)f2bf(f1.y);
    o[6] = (short)f2bf(f1.z); o[7] = (short)f2bf(f1.w);
    *(short8*)(wb + (size_t)idx * 8) = o;
    return;
  }

  // cvtx: xb[Mp][768] bf16; pad rows (>= M) zero-filled.
  {
    int idx = (bid - gE - gW) * 256 + tid;   // unit of 8 elems
    int total = Mp * (D_IN / 8);
    if (idx >= total) return;
    int row = idx / (D_IN / 8);
    short8 o;
    if (row < M) {
      int col = (idx % (D_IN / 8)) * 8;
      const float* p = x + (size_t)row * D_IN + col;
      float4 f0 = *(const float4*)p;
      float4 f1 = *(const float4*)(p + 4);
      o[0] = (short)f2bf(f0.x); o[1] = (short)f2bf(f0.y);
      o[2] = (short)f2bf(f0.z); o[3] = (short)f2bf(f0.w);
      o[4] = (short)f2bf(f1.x); o[5] = (short)f2bf(f1.y);
      o[6] = (short)f2bf(f1.z); o[7] = (short)f2bf(f1.w);
    } else {
      o = (short8)0;
    }
    *(short8*)(xb + (size_t)idx * 8) = o;
  }
}

// ----- hierarchical exclusive scan of counts[M] -> offs, cursor ------------
__global__ void scanA_k(const int* __restrict__ counts,
                        int* __restrict__ blockSums, int M) {
  __shared__ int ts[256];
  int b = blockIdx.x, t = threadIdx.x;
  int base = b * 1024 + t * 4;
  int s = 0;
#pragma unroll
  for (int k = 0; k < 4; k++) { int i = base + k; if (i < M) s += counts[i]; }
  ts[t] = s;
  __syncthreads();
  for (int off = 128; off > 0; off >>= 1) {
    if (t < off) ts[t] += ts[t + off];
    __syncthreads();
  }
  if (t == 0) blockSums[b] = ts[0];
}

__global__ void scanC_k(const int* __restrict__ counts,
                        const int* __restrict__ bsums,
                        int* __restrict__ offs, int* __restrict__ cursor,
                        int M, int E, int nb) {
  __shared__ int ts[256];
  __shared__ int bofs;
  int b = blockIdx.x, t = threadIdx.x;
  if (t < 64) {
    int v = (t < nb) ? bsums[t] : 0;
    int orig = v;
#pragma unroll
    for (int off = 1; off < 64; off <<= 1) {
      int u = __shfl_up(v, off);
      if (t >= off) v += u;
    }
    if (t == b) bofs = v - orig;
  }
  int base = b * 1024 + t * 4;
  int v[4]; int s = 0;
#pragma unroll
  for (int k = 0; k < 4; k++) {
    int i = base + k;
    v[k] = (i < M) ? counts[i] : 0;
    s += v[k];
  }
  ts[t] = s;
  __syncthreads();
  for (int off = 1; off < 256; off <<= 1) {
    int x = (t >= off) ? ts[t - off] : 0;
    __syncthreads();
    ts[t] += x;
    __syncthreads();
  }
  int run = bofs + ts[t] - s;
#pragma unroll
  for (int k = 0; k < 4; k++) {
    int i = base + k;
    if (i < M) { offs[i] = run; cursor[i] = run; run += v[k]; }
  }
  if (b == 0 && t == 0) offs[M] = E;
}

__global__ void fill_k(const int* __restrict__ src, const int* __restrict__ dst,
                       int* __restrict__ cursor, int* __restrict__ csr, int E) {
  int i = blockIdx.x * 256 + threadIdx.x;
  if (i >= E) return;
  int pos = atomicAdd(&cursor[dst[i]], 1);
  csr[pos] = src[i];
}

// --------------------------- layer-1 GEMM ----------------------------------
// Cl[Mp,256]/Cr[Mp,256](bf16) = xb[Mp,768] @ wb[512,768]^T (split at col 256)
// 128x128 tile, BK=64, 8 waves (512 thr), wave tile 64x32 (grid 2x4),
// 4x2x2 of 16x16x32 MFMA, acc[4][2] = 32 AGPR.
// A LDS [128][64] row-major, XOR chunk-swizzle: slot [row][c] holds global
//   k-chunk (c ^ (row&7)) of the body's 64-wide slice. Staging thread g
//   (row=g>>3, c=g&7) FETCHES chunk (g&7)^(row&7) -> linear LDS dst g*8;
//   read of chunk kq uses slot kq^(row&7). 128B-coalesced, banks balanced.
// B LDS segmented: short off = cb*1024 + s*512 + quad*128 + l15*8; staging
//   thread h: cb=h>>7, s=(h>>6)&1, q=(h>>4)&3, l=h&15 -> wb row cb*16+l,
//   k chunk s*4+q (R12-proven map per k-half).
// Body kk (P=kk&1): 12 ds_read frags buf[P]; lgkm(0); barrier;
//   STAGE(kk+2)->buf[P] (4 asyncs/thread); 16 MFMA; vmcnt(4); barrier.
// Tail: body10 vmcnt(0), body11 bare. LDS 64KB -> 2 blocks/CU (= VGPR-bin
// residency, free). XCD-aware bid map.
__global__ __launch_bounds__(512, 4) void gemm_k(
    const unsigned short* __restrict__ xb,
    const unsigned short* __restrict__ wb,
    unsigned short* __restrict__ Cl, unsigned short* __restrict__ Cr,
    int MT, int mtPerXcd) {
  __shared__ unsigned short As[2][128 * 64];   // 32 KB
  __shared__ unsigned short Bs[2][128 * 64];   // 32 KB

  const int bid = blockIdx.x;
  const int xcd = bid & 7;
  const int j   = bid >> 3;
  const int mt  = xcd * mtPerXcd + (j >> 2);
  if (mt >= MT) return;
  const int m0 = mt * 128;
  const int n0 = (j & 3) * 128;

  const int tid  = threadIdx.x;       // 0..511
  const int lane = tid & 63;
  const int wid  = tid >> 6;          // 0..7
  const int wr = wid >> 2, wc = wid & 3;   // wave grid 2 x 4, tile 64x32
  const int l15  = lane & 15;
  const int quad = lane >> 4;

  // A granules: g0 = tid, g1 = tid+512. row = g>>3, cl = g&7 (linear chunk),
  // fetched chunk cf = cl ^ (row&7). LDS dst = g*8 shorts.
  const int ar0 = tid >> 3, ac0 = (tid & 7) ^ (ar0 & 7);
  const int ar1 = (tid + 512) >> 3, ac1 = (tid & 7) ^ (ar1 & 7);
  const unsigned short* axp0 = xb + (size_t)(m0 + ar0) * D_IN + ac0 * 8;
  const unsigned short* axp1 = xb + (size_t)(m0 + ar1) * D_IN + ac1 * 8;
  const int aoff0 = tid * 8;
  const int aoff1 = (tid + 512) * 8;

  // B granules: h0 = tid, h1 = tid+512.
  //   cb = h>>7, s = (h>>6)&1, q = (h>>4)&3, l = h&15
  const int h1 = tid + 512;
  const int brow0 = ((tid >> 7) << 4) + (tid & 15);
  const int bk0   = (((tid >> 6) & 1) << 5) + (((tid >> 4) & 3) << 3);
  const int brow1 = ((h1 >> 7) << 4) + (h1 & 15);
  const int bk1   = (((h1 >> 6) & 1) << 5) + (((h1 >> 4) & 3) << 3);
  const unsigned short* bgp0 = wb + (size_t)(n0 + brow0) * D_IN + bk0;
  const unsigned short* bgp1 = wb + (size_t)(n0 + brow1) * D_IN + bk1;
  const int boff0 = tid * 8;
  const int boff1 = (tid + 512) * 8;

  f32x4 acc[4][2];
#pragma unroll
  for (int r = 0; r < 4; r++)
#pragma unroll
    for (int c = 0; c < 2; c++) acc[r][c] = (f32x4)0.0f;

#define STAGE(P, kk)                                                          \
  {                                                                           \
    const int kn = (kk) * 64;                                                 \
    async_copy16(axp0 + kn, &As[P][aoff0]);                                   \
    async_copy16(axp1 + kn, &As[P][aoff1]);                                   \
    async_copy16(bgp0 + kn, &Bs[P][boff0]);                                   \
    async_copy16(bgp1 + kn, &Bs[P][boff1]);                                   \
  }

  // A read: a[r][s]: row = wr*64 + r*16 + l15; chunk kq = s*4 + quad;
  //   slot chunk = kq ^ (row&7) = kq ^ (l15&7); offset = row*64 + slot*8.
#define READ_FRAGS(P, a, b)                                                   \
  _Pragma("unroll")                                                           \
  for (int r = 0; r < 4; r++)                                                 \
    _Pragma("unroll")                                                         \
    for (int s = 0; s < 2; s++)                                               \
      a[r][s] = *(const short8*)&As[P][(wr * 64 + r * 16 + l15) * 64 +        \
                                       ((s * 4 + quad) ^ (l15 & 7)) * 8];     \
  _Pragma("unroll")                                                           \
  for (int c = 0; c < 2; c++)                                                 \
    _Pragma("unroll")                                                         \
    for (int s = 0; s < 2; s++)                                               \
      b[c][s] = *(const short8*)&Bs[P][(wc * 2 + c) * 1024 + s * 512 +        \
                                       quad * 128 + l15 * 8];

#define MFMA16(a, b)                                                          \
  _Pragma("unroll")                                                           \
  for (int s = 0; s < 2; s++)                                                 \
    _Pragma("unroll")                                                         \
    for (int r = 0; r < 4; r++)                                               \
      _Pragma("unroll")                                                       \
      for (int c = 0; c < 2; c++)                                             \
        acc[r][c] = __builtin_amdgcn_mfma_f32_16x16x32_bf16(a[r][s], b[c][s], \
                                                            acc[r][c], 0, 0, 0);

#define GEMM_BODY(P, kk, VM)                                                  \
  {                                                                           \
    short8 a[4][2], b[2][2];                                                  \
    READ_FRAGS(P, a, b)                                                       \
    asm volatile("s_waitcnt lgkmcnt(0)" ::: "memory");                        \
    __builtin_amdgcn_s_barrier();                                             \
    if ((kk) + 2 < KBODY) { STAGE(P, (kk) + 2) }                              \
    MFMA16(a, b)                                                              \
    asm volatile("s_waitcnt vmcnt(" #VM ")" ::: "memory");                    \
    __builtin_amdgcn_s_barrier();                                             \
  }

  // prologue: stage(0)->buf0, stage(1)->buf1 (8 asyncs/thread total);
  // vmcnt(4) drains stage(0) while stage(1) stays in flight; barrier.
  STAGE(0, 0)
  STAGE(1, 1)
  asm volatile("s_waitcnt vmcnt(4)" ::: "memory");
  __builtin_amdgcn_s_barrier();

  // bodies 0..9 stage kk+2 (<=11), steady vmcnt(4)
  for (int it = 0; it < KBODY - 2; it += 2) {
    GEMM_BODY(0, it, 4)
    GEMM_BODY(1, it + 1, 4)
  }
  // tail: body 10 (buf0; stage(11) in flight) drains vmcnt(0); body 11 bare
  {
    short8 a[4][2], b[2][2];
    READ_FRAGS(0, a, b)
    asm volatile("s_waitcnt lgkmcnt(0)" ::: "memory");
    MFMA16(a, b)
    asm volatile("s_waitcnt vmcnt(0)" ::: "memory");   // stage(11) landed
    __builtin_amdgcn_s_barrier();                      // ...for ALL waves
  }
  {
    short8 a[4][2], b[2][2];
    READ_FRAGS(1, a, b)
    asm volatile("s_waitcnt lgkmcnt(0)" ::: "memory");
    MFMA16(a, b)
  }
#undef GEMM_BODY
#undef MFMA16
#undef READ_FRAGS
#undef STAGE

  // epilogue: C/D layout col=lane&15, row=(lane>>4)*4+reg; store bf16.
  // n0 in {0,128} -> Cl, {256,384} -> Cr; column base = n0 & 255 (n0%256).
  unsigned short* dstC = (n0 < 256) ? Cl : Cr;
  const int ncb = n0 & 255;
  const int crow0 = m0 + wr * 64;
  const int ccol0 = ncb + wc * 32;
#pragma unroll
  for (int r = 0; r < 4; r++)
#pragma unroll
    for (int c = 0; c < 2; c++) {
      int col = ccol0 + c * 16 + l15;
#pragma unroll
      for (int reg = 0; reg < 4; reg++) {
        int row = crow0 + r * 16 + quad * 4 + reg;
        dstC[(size_t)row * D_HID + col] = f2bf(acc[r][c][reg]);
      }
    }
}

// --------------------- fused aggregate + epilogue + layer-2 ----------------
// h[c] = relu( mean_{j in N(i)} Cl[j][c] + b1[c] + Cr[i][c] )   (registers)
// rs[i] = { h@W2_l[0], h@W2_l[1], h@W2_r[0], h@W2_r[1] }
// one wave per node; lane-parallel csr fetch + __shfl broadcast, 4 gathers
// in flight.
__global__ void agg_l2_k(const unsigned short* __restrict__ Cl,
                         const unsigned short* __restrict__ Cr,
                         const int* __restrict__ offs, const int* __restrict__ csr,
                         const float* __restrict__ b1,
                         const float* __restrict__ W2l, const float* __restrict__ W2r,
                         float4* __restrict__ rs, int M) {
  int tid = threadIdx.x;
  int lane = tid & 63;
  int wid = tid >> 6;
  int i = blockIdx.x * 4 + wid;
  if (i >= M) return;
  int c = lane * 4;
  float4 bv  = *(const float4*)(b1 + c);
  float4 wl0 = *(const float4*)(W2l + c);
  float4 wl1 = *(const float4*)(W2l + D_HID + c);
  float4 wr0 = *(const float4*)(W2r + c);
  float4 wr1 = *(const float4*)(W2r + D_HID + c);
  int s = offs[i], e = offs[i + 1];
  ushort4 q = *(const ushort4*)(Cr + (size_t)i * D_HID + c);  // self row early
  float a0x = 0.f, a0y = 0.f, a0z = 0.f, a0w = 0.f;
  float a1x = 0.f, a1y = 0.f, a1z = 0.f, a1w = 0.f;
  float a2x = 0.f, a2y = 0.f, a2z = 0.f, a2w = 0.f;
  float a3x = 0.f, a3y = 0.f, a3z = 0.f, a3w = 0.f;
  for (int base = s; base < e; base += 64) {
    int rem = e - base;
    int m = rem < 64 ? rem : 64;
    int jj = csr[base + (lane < m ? lane : m - 1)];  // coalesced, in-bounds
    int t = 0;
    for (; t + 4 <= m; t += 4) {
      int j0 = __shfl(jj, t);
      int j1 = __shfl(jj, t + 1);
      int j2 = __shfl(jj, t + 2);
      int j3 = __shfl(jj, t + 3);
      ushort4 v0 = *(const ushort4*)(Cl + (size_t)j0 * D_HID + c);
      ushort4 v1 = *(const ushort4*)(Cl + (size_t)j1 * D_HID + c);
      ushort4 v2 = *(const ushort4*)(Cl + (size_t)j2 * D_HID + c);
      ushort4 v3 = *(const ushort4*)(Cl + (size_t)j3 * D_HID + c);
      a0x += bf2f(v0.x); a0y += bf2f(v0.y); a0z += bf2f(v0.z); a0w += bf2f(v0.w);
      a1x += bf2f(v1.x); a1y += bf2f(v1.y); a1z += bf2f(v1.z); a1w += bf2f(v1.w);
      a2x += bf2f(v2.x); a2y += bf2f(v2.y); a2z += bf2f(v2.z); a2w += bf2f(v2.w);
      a3x += bf2f(v3.x); a3y += bf2f(v3.y); a3z += bf2f(v3.z); a3w += bf2f(v3.w);
    }
    for (; t < m; t++) {
      int j0 = __shfl(jj, t);
      ushort4 v = *(const ushort4*)(Cl + (size_t)j0 * D_HID + c);
      a0x += bf2f(v.x); a0y += bf2f(v.y); a0z += bf2f(v.z); a0w += bf2f(v.w);
    }
  }
  float ax = (a0x + a1x) + (a2x + a3x);
  float ay = (a0y + a1y) + (a2y + a3y);
  float az = (a0z + a1z) + (a2z + a3z);
  float aw = (a0w + a1w) + (a2w + a3w);
  float inv = 1.0f / fmaxf((float)(e - s), 1.0f);
  float h0 = fmaxf(ax * inv + bv.x + bf2f(q.x), 0.0f);
  float h1 = fmaxf(ay * inv + bv.y + bf2f(q.y), 0.0f);
  float h2 = fmaxf(az * inv + bv.z + bf2f(q.z), 0.0f);
  float h3 = fmaxf(aw * inv + bv.w + bf2f(q.w), 0.0f);
  float r0 = h0 * wl0.x + h1 * wl0.y + h2 * wl0.z + h3 * wl0.w;
  float r1 = h0 * wl1.x + h1 * wl1.y + h2 * wl1.z + h3 * wl1.w;
  float s0 = h0 * wr0.x + h1 * wr0.y + h2 * wr0.z + h3 * wr0.w;
  float s1 = h0 * wr1.x + h1 * wr1.y + h2 * wr1.z + h3 * wr1.w;
#pragma unroll
  for (int off = 32; off > 0; off >>= 1) {
    r0 += __shfl_xor(r0, off);
    r1 += __shfl_xor(r1, off);
    s0 += __shfl_xor(s0, off);
    s1 += __shfl_xor(s1, off);
  }
  if (lane == 0) rs[i] = make_float4(r0, r1, s0, s1);
}

// --------------------------- final -----------------------------------------
// out[i][j] = mean_{k in N(i)} rs[k][j] + b2[j] + rs[i][2+j]
__global__ void final_k(const float4* __restrict__ rs, const int* __restrict__ offs,
                        const int* __restrict__ csr, const float* __restrict__ b2,
                        float* __restrict__ out, int M) {
  int i = blockIdx.x * 256 + threadIdx.x;
  if (i >= M) return;
  int s = offs[i], e = offs[i + 1];
  float a0 = 0.0f, a1 = 0.0f, b0 = 0.0f, b1 = 0.0f;
  int t = s;
  for (; t + 2 <= e; t += 2) {
    float4 v0 = rs[csr[t]];
    float4 v1 = rs[csr[t + 1]];
    a0 += v0.x; a1 += v0.y;
    b0 += v1.x; b1 += v1.y;
  }
  if (t < e) { float4 v = rs[csr[t]]; a0 += v.x; a1 += v.y; }
  a0 += b0; a1 += b1;
  float inv = 1.0f / fmaxf((float)(e - s), 1.0f);
  float4 me = rs[i];
  out[2 * i + 0] = a0 * inv + b2[0] + me.z;
  out[2 * i + 1] = a1 * inv + b2[1] + me.w;
}

// ---------------------------------------------------------------------------

extern "C" void kernel_launch(void* const* d_in, const int* in_sizes, int n_in,
                              void* d_out, int out_size, void* d_ws, size_t ws_size,
                              hipStream_t stream) {
  const float* x   = (const float*)d_in[0];
  const void*  eix = d_in[1];
  const float* W1l = (const float*)d_in[2];
  const float* b1  = (const float*)d_in[3];
  const float* W1r = (const float*)d_in[4];
  const float* W2l = (const float*)d_in[5];
  const float* b2  = (const float*)d_in[6];
  const float* W2r = (const float*)d_in[7];
  float* out = (float*)d_out;

  const int M  = in_sizes[0] / D_IN;       // 50000
  const int E  = in_sizes[1] / 2;          // 250000
  const int Mp = ((M + 127) / 128) * 128;  // 50048
  const int nb = (M + 1023) / 1024;        // scan blocks (<=64)
  const int MT = Mp / 128;                 // 391 m-tiles
  const int mtPerXcd = (MT + 7) / 8;       // 49
  const int gemmBlocks = 8 * mtPerXcd * 4; // 1568 (some return early)

  // workspace layout (256B aligned slots)
  char* ws = (char*)d_ws;
  size_t off = 0;
  auto alloc = [&](size_t b) { size_t o = off; off += (b + 255) & ~(size_t)255; return o; };
  size_t oCounts = alloc((size_t)M * 4);
  size_t zeroBytes = (size_t)M * 4;        // counts
  size_t oOffs   = alloc((size_t)(M + 1) * 4);
  size_t oCursor = alloc((size_t)M * 4);
  size_t oCsr    = alloc((size_t)E * 4);
  size_t oSrc    = alloc((size_t)E * 4);
  size_t oDst    = alloc((size_t)E * 4);
  size_t oBSums  = alloc(64 * 4);
  size_t oWb     = alloc((size_t)N1 * D_IN * 2);
  size_t oCl     = alloc((size_t)Mp * D_HID * 2);  // bf16 neighbor half
  size_t oCr     = alloc((size_t)Mp * D_HID * 2);  // bf16 self half
  size_t oRs     = alloc((size_t)M * 16);
  size_t oXb     = alloc((size_t)Mp * D_IN * 2);   // bf16 x, padded
  (void)ws_size; (void)n_in; (void)out_size;

  int* counts = (int*)(ws + oCounts);
  int* offs   = (int*)(ws + oOffs);
  int* cursor = (int*)(ws + oCursor);
  int* csr    = (int*)(ws + oCsr);
  int* src32  = (int*)(ws + oSrc);
  int* dst32  = (int*)(ws + oDst);
  int* bsums  = (int*)(ws + oBSums);
  unsigned short* wb = (unsigned short*)(ws + oWb);
  unsigned short* Cl = (unsigned short*)(ws + oCl);
  unsigned short* Cr = (unsigned short*)(ws + oCr);
  float4* rs = (float4*)(ws + oRs);
  unsigned short* xb = (unsigned short*)(ws + oXb);

  hipMemsetAsync(counts, 0, zeroBytes, stream);

  int gE = (E + 255) / 256;                         // 977
  int gW = (N1 * (D_IN / 8) + 255) / 256;           // 192
  int gX = (Mp * (D_IN / 8) + 255) / 256;           // 18768
  prep_k<<<gE + gW + gX, 256, 0, stream>>>(eix, src32, dst32, counts, E,
                                           W1l, W1r, wb, x, xb, M, Mp, gE, gW);
  scanA_k<<<nb, 256, 0, stream>>>(counts, bsums, M);
  scanC_k<<<nb, 256, 0, stream>>>(counts, bsums, offs, cursor, M, E, nb);
  fill_k<<<(E + 255) / 256, 256, 0, stream>>>(src32, dst32, cursor, csr, E);

  gemm_k<<<gemmBlocks, 512, 0, stream>>>(xb, wb, Cl, Cr, MT, mtPerXcd);

  agg_l2_k<<<(M + 3) / 4, 256, 0, stream>>>(Cl, Cr, offs, csr, b1, W2l, W2r,
                                            rs, M);
  final_k<<<(M + 255) / 256, 256, 0, stream>>>(rs, offs, csr, b2, out, M);
}

// Round 13
// 359.874 us; speedup vs baseline: 1.0164x; 1.0164x over previous
//
#include <hip/hip_runtime.h>
#include <stdint.h>

// ---------------------------------------------------------------------------
// GraphSAGE 2-layer: out = SAGE2(relu(SAGE1(x)))
// SAGE(x) = mean_agg(x@W_l.T) + b + x@W_r.T   (project-then-aggregate rewrite)
// R19 == R16 verbatim (best verified: 362.0us). Session ledger:
//  - gemm: m97-structure dbuf-2 counted-vmcnt, 8 waves x 64x32 per 128x128
//    tile (512 thr, launch_bounds(512,4)) -> unified regs < 128-VGPR HW bin,
//    16 waves/CU. R15 (depth-3): flat. R17 (64-bin, 32 waves/CU): flat.
//    R18 (BK=64, half barriers): -1%. R13/R14 (fused x->bf16): negative.
//  - cvtx pre-pass (bf16 xb) beats any in-gemm convert; prep fuses
//    cvtidx|cvtw|cvtx by block range.
//  - Cl/Cr split output (column base = n0 & 255 -- NOT &127), lane-parallel
//    csr gather in agg_l2, counted-vmcnt everywhere, no min-waves bounds on
//    register-heavy kernels (R7 spill lesson).
// ---------------------------------------------------------------------------

#define D_IN  768
#define D_HID 256
#define N1    512   // concat(W1_l, W1_r) output width
#define KITERS (D_IN / 32)   // 24

typedef __attribute__((ext_vector_type(8))) short short8;
typedef __attribute__((ext_vector_type(4))) float f32x4;

__device__ __forceinline__ void async_copy16(const void* g, void* l) {
  __builtin_amdgcn_global_load_lds(
      (const __attribute__((address_space(1))) unsigned int*)g,
      (__attribute__((address_space(3))) unsigned int*)l,
      16, 0, 0);
}

__device__ __forceinline__ unsigned short f2bf(float f) {
  union { float f; unsigned u; } v; v.f = f;
  unsigned r = v.u + 0x7FFFu + ((v.u >> 16) & 1u);   // RNE
  return (unsigned short)(r >> 16);
}

__device__ __forceinline__ float bf2f(unsigned short b) {
  union { unsigned u; float f; } v; v.u = ((unsigned)b) << 16;
  return v.f;
}

// ------------------- fused prep: cvtidx | cvtw | cvtx ----------------------
// Three independent streaming jobs in one launch, selected by block range:
//   [0, gE)            edge-index convert + degree count
//   [gE, gE+gW)        W1 -> bf16 wb
//   [gE+gW, gE+gW+gX)  x -> bf16 xb (padded to Mp rows)
__global__ void prep_k(const void* __restrict__ eidx,
                       int* __restrict__ src32, int* __restrict__ dst32,
                       int* __restrict__ counts, int E,
                       const float* __restrict__ W1l, const float* __restrict__ W1r,
                       unsigned short* __restrict__ wb,
                       const float* __restrict__ x,
                       unsigned short* __restrict__ xb, int M, int Mp,
                       int gE, int gW) {
  const int tid = threadIdx.x;
  const int bid = blockIdx.x;

  if (bid < gE) {
    // cvtidx: block-local int64/int32 detection (int64 LE: odd words 0)
    __shared__ int flag32;
    int i = bid * 256 + tid;
    unsigned v = (i < E) ? ((const unsigned int*)eidx)[2 * (size_t)i + 1] : 0u;
    unsigned long long any = __ballot(v != 0u);
    if (tid == 0) flag32 = 0;
    __syncthreads();
    if ((tid & 63) == 0 && any) flag32 = 1;  // benign multi-writer
    __syncthreads();
    if (i >= E) return;
    int s, d;
    if (flag32) {
      const int* p = (const int*)eidx;
      s = p[i]; d = p[E + i];
    } else {
      const long long* p = (const long long*)eidx;
      s = (int)p[i]; d = (int)p[E + i];
    }
    src32[i] = s;
    dst32[i] = d;
    atomicAdd(&counts[d], 1);
    return;
  }

  if (bid < gE + gW) {
    // cvtw: wb rows 0..255 = W1_l, 256..511 = W1_r (each [256,768])
    int idx = (bid - gE) * 256 + tid;
    int total = N1 * (D_IN / 8);
    if (idx >= total) return;
    int row = idx / (D_IN / 8);
    int cpos = (idx % (D_IN / 8)) * 8;
    const float* p = (row < D_HID) ? (W1l + (size_t)row * D_IN + cpos)
                                   : (W1r + (size_t)(row - D_HID) * D_IN + cpos);
    float4 f0 = *(const float4*)p;
    float4 f1 = *(const float4*)(p + 4);
    short8 o;
    o[0] = (short)f2bf(f0.x); o[1] = (short)f2bf(f0.y);
    o[2] = (short)f2bf(f0.z); o[3] = (short)f2bf(f0.w);
    o[4] = (short)f2bf(f1.x); o[5] = (short)f2bf(f1.y);
    o[6] = (short)f2bf(f1.z); o[7] = (short)f2bf(f1.w);
    *(short8*)(wb + (size_t)idx * 8) = o;
    return;
  }

  // cvtx: xb[Mp][768] bf16; pad rows (>= M) zero-filled.
  {
    int idx = (bid - gE - gW) * 256 + tid;   // unit of 8 elems
    int total = Mp * (D_IN / 8);
    if (idx >= total) return;
    int row = idx / (D_IN / 8);
    short8 o;
    if (row < M) {
      int col = (idx % (D_IN / 8)) * 8;
      const float* p = x + (size_t)row * D_IN + col;
      float4 f0 = *(const float4*)p;
      float4 f1 = *(const float4*)(p + 4);
      o[0] = (short)f2bf(f0.x); o[1] = (short)f2bf(f0.y);
      o[2] = (short)f2bf(f0.z); o[3] = (short)f2bf(f0.w);
      o[4] = (short)f2bf(f1.x); o[5] = (short)f2bf(f1.y);
      o[6] = (short)f2bf(f1.z); o[7] = (short)f2bf(f1.w);
    } else {
      o = (short8)0;
    }
    *(short8*)(xb + (size_t)idx * 8) = o;
  }
}

// ----- hierarchical exclusive scan of counts[M] -> offs, cursor ------------
__global__ void scanA_k(const int* __restrict__ counts,
                        int* __restrict__ blockSums, int M) {
  __shared__ int ts[256];
  int b = blockIdx.x, t = threadIdx.x;
  int base = b * 1024 + t * 4;
  int s = 0;
#pragma unroll
  for (int k = 0; k < 4; k++) { int i = base + k; if (i < M) s += counts[i]; }
  ts[t] = s;
  __syncthreads();
  for (int off = 128; off > 0; off >>= 1) {
    if (t < off) ts[t] += ts[t + off];
    __syncthreads();
  }
  if (t == 0) blockSums[b] = ts[0];
}

__global__ void scanC_k(const int* __restrict__ counts,
                        const int* __restrict__ bsums,
                        int* __restrict__ offs, int* __restrict__ cursor,
                        int M, int E, int nb) {
  __shared__ int ts[256];
  __shared__ int bofs;
  int b = blockIdx.x, t = threadIdx.x;
  if (t < 64) {
    int v = (t < nb) ? bsums[t] : 0;
    int orig = v;
#pragma unroll
    for (int off = 1; off < 64; off <<= 1) {
      int u = __shfl_up(v, off);
      if (t >= off) v += u;
    }
    if (t == b) bofs = v - orig;
  }
  int base = b * 1024 + t * 4;
  int v[4]; int s = 0;
#pragma unroll
  for (int k = 0; k < 4; k++) {
    int i = base + k;
    v[k] = (i < M) ? counts[i] : 0;
    s += v[k];
  }
  ts[t] = s;
  __syncthreads();
  for (int off = 1; off < 256; off <<= 1) {
    int x = (t >= off) ? ts[t - off] : 0;
    __syncthreads();
    ts[t] += x;
    __syncthreads();
  }
  int run = bofs + ts[t] - s;
#pragma unroll
  for (int k = 0; k < 4; k++) {
    int i = base + k;
    if (i < M) { offs[i] = run; cursor[i] = run; run += v[k]; }
  }
  if (b == 0 && t == 0) offs[M] = E;
}

__global__ void fill_k(const int* __restrict__ src, const int* __restrict__ dst,
                       int* __restrict__ cursor, int* __restrict__ csr, int E) {
  int i = blockIdx.x * 256 + threadIdx.x;
  if (i >= E) return;
  int pos = atomicAdd(&cursor[dst[i]], 1);
  csr[pos] = src[i];
}

// --------------------------- layer-1 GEMM ----------------------------------
// Cl[Mp,256]/Cr[Mp,256](bf16) = xb[Mp,768] @ wb[512,768]^T (split at col 256)
// 128x128 tile, BK=32, EIGHT waves (512 thr), wave tile 64x32 (grid 2x4),
// 4x2 of 16x16x32 MFMA -> acc = 32 AGPR/thread. Unified regs < 128 -> 4
// waves/SIMD HW bin (16 waves/CU); __launch_bounds__(512,4) enforces the 128
// budget. m97-structure dbuf-2 counted-vmcnt schedule:
//   body kk (P=kk&1): ds_read frags buf[P]; lgkm(0); barrier;
//     STAGE(kk+2)->buf[P] (2x global_load_lds w16/thread); 8x MFMA;
//     vmcnt(2); barrier    (outstanding 4 -> drains stage(kk+1))
// Tail: body22 vmcnt(0), body23 bare. LDS 32KB. XCD-aware bid map: xcd=bid&7
// owns contiguous m-tiles; 4 n-blocks of an m-tile adjacent on one XCD.
__global__ __launch_bounds__(512, 4) void gemm_k(
    const unsigned short* __restrict__ xb,
    const unsigned short* __restrict__ wb,
    unsigned short* __restrict__ Cl, unsigned short* __restrict__ Cr,
    int MT, int mtPerXcd) {
  __shared__ unsigned short As[2][128 * 32];   // 16 KB
  __shared__ unsigned short Bs[2][128 * 32];   // 16 KB

  const int bid = blockIdx.x;
  const int xcd = bid & 7;
  const int j   = bid >> 3;
  const int mt  = xcd * mtPerXcd + (j >> 2);
  if (mt >= MT) return;
  const int m0 = mt * 128;
  const int n0 = (j & 3) * 128;

  const int tid  = threadIdx.x;       // 0..511
  const int lane = tid & 63;
  const int wid  = tid >> 6;          // 0..7
  const int wr = wid >> 2, wc = wid & 3;   // wave grid 2 x 4, tile 64x32
  const int l15  = lane & 15;
  const int quad = lane >> 4;

  // A: ONE granule/thread (g = tid): row = tid>>2, kg = tid&3;
  // LDS linear row-major [128][32] bf16 -> short offset tid*8.
  const unsigned short* axp = xb + (size_t)(m0 + (tid >> 2)) * D_IN + (tid & 3) * 8;
  const int aoff = tid * 8;

  // B: ONE granule/thread (h = tid), R12's K-major segment map generalized:
  //   row(h) = ((h&255)>>6)*16 + (h&15) + (h>>8)*64,  kg(h) = (h>>4)&3
  const int brow = (((tid & 255) >> 6) << 4) + (tid & 15) + ((tid >> 8) << 6);
  const int bcg  = (tid >> 4) & 3;
  const unsigned short* bgp = wb + (size_t)(n0 + brow) * D_IN + bcg * 8;
  const int boff = tid * 8;

  f32x4 acc[4][2];
#pragma unroll
  for (int r = 0; r < 4; r++)
#pragma unroll
    for (int c = 0; c < 2; c++) acc[r][c] = (f32x4)0.0f;

#define STAGE(P, kk)                                                          \
  {                                                                           \
    const int kn = (kk) * 32;                                                 \
    async_copy16(axp + kn, &As[P][aoff]);                                     \
    async_copy16(bgp + kn, &Bs[P][boff]);                                     \
  }

#define READ_FRAGS(P, a, b)                                                   \
  _Pragma("unroll")                                                           \
  for (int r = 0; r < 4; r++)                                                 \
    a[r] = *(const short8*)&As[P][(wr * 64 + r * 16 + l15) * 32 + quad * 8];  \
  _Pragma("unroll")                                                           \
  for (int c = 0; c < 2; c++)                                                 \
    b[c] = *(const short8*)&Bs[P][(wc * 2 + c) * 512 + quad * 128 + l15 * 8];

#define MFMA8(a, b)                                                           \
  _Pragma("unroll")                                                           \
  for (int r = 0; r < 4; r++)                                                 \
    _Pragma("unroll")                                                         \
    for (int c = 0; c < 2; c++)                                               \
      acc[r][c] = __builtin_amdgcn_mfma_f32_16x16x32_bf16(a[r], b[c],         \
                                                          acc[r][c], 0, 0, 0);

#define GEMM_BODY(P, kk)                                                      \
  {                                                                           \
    short8 a[4], b[2];                                                        \
    READ_FRAGS(P, a, b)                                                       \
    asm volatile("s_waitcnt lgkmcnt(0)" ::: "memory");                        \
    __builtin_amdgcn_s_barrier();                                             \
    STAGE(P, (kk) + 2)                                                        \
    MFMA8(a, b)                                                               \
    asm volatile("s_waitcnt vmcnt(2)" ::: "memory");                          \
    __builtin_amdgcn_s_barrier();                                             \
  }

  // prologue: stage(0)->buf0, stage(1)->buf1 (4 asyncs); vmcnt(2) drains
  // stage(0) while stage(1) stays in flight; barrier.
  STAGE(0, 0)
  STAGE(1, 1)
  asm volatile("s_waitcnt vmcnt(2)" ::: "memory");
  __builtin_amdgcn_s_barrier();

  // main loop: bodies 0..21 (stage kk+2 <= 23 always valid)
  for (int it = 0; it < KITERS - 2; it += 2) {
    GEMM_BODY(0, it)
    GEMM_BODY(1, it + 1)
  }
#undef GEMM_BODY

  // tail: body 22 (buf0; stage(23) already in flight), then body 23 (buf1)
  {
    short8 a[4], b[2];
    READ_FRAGS(0, a, b)
    MFMA8(a, b)
    asm volatile("s_waitcnt vmcnt(0)" ::: "memory");   // stage(23) landed
    __builtin_amdgcn_s_barrier();                      // ...for ALL waves
  }
  {
    short8 a[4], b[2];
    READ_FRAGS(1, a, b)
    MFMA8(a, b)
  }
#undef MFMA8
#undef READ_FRAGS
#undef STAGE

  // epilogue: C/D layout col=lane&15, row=(lane>>4)*4+reg; store bf16.
  // n0 in {0,128} -> Cl, {256,384} -> Cr; column base = n0 & 255 (n0%256).
  unsigned short* dstC = (n0 < 256) ? Cl : Cr;
  const int ncb = n0 & 255;
  const int crow0 = m0 + wr * 64;
  const int ccol0 = ncb + wc * 32;
#pragma unroll
  for (int r = 0; r < 4; r++)
#pragma unroll
    for (int c = 0; c < 2; c++) {
      int col = ccol0 + c * 16 + l15;
#pragma unroll
      for (int reg = 0; reg < 4; reg++) {
        int row = crow0 + r * 16 + quad * 4 + reg;
        dstC[(size_t)row * D_HID + col] = f2bf(acc[r][c][reg]);
      }
    }
}

// --------------------- fused aggregate + epilogue + layer-2 ----------------
// h[c] = relu( mean_{j in N(i)} Cl[j][c] + b1[c] + Cr[i][c] )   (registers)
// rs[i] = { h@W2_l[0], h@W2_l[1], h@W2_r[0], h@W2_r[1] }
// one wave per node; lane-parallel csr fetch + __shfl broadcast, 4 gathers
// in flight.
__global__ void agg_l2_k(const unsigned short* __restrict__ Cl,
                         const unsigned short* __restrict__ Cr,
                         const int* __restrict__ offs, const int* __restrict__ csr,
                         const float* __restrict__ b1,
                         const float* __restrict__ W2l, const float* __restrict__ W2r,
                         float4* __restrict__ rs, int M) {
  int tid = threadIdx.x;
  int lane = tid & 63;
  int wid = tid >> 6;
  int i = blockIdx.x * 4 + wid;
  if (i >= M) return;
  int c = lane * 4;
  float4 bv  = *(const float4*)(b1 + c);
  float4 wl0 = *(const float4*)(W2l + c);
  float4 wl1 = *(const float4*)(W2l + D_HID + c);
  float4 wr0 = *(const float4*)(W2r + c);
  float4 wr1 = *(const float4*)(W2r + D_HID + c);
  int s = offs[i], e = offs[i + 1];
  ushort4 q = *(const ushort4*)(Cr + (size_t)i * D_HID + c);  // self row early
  float a0x = 0.f, a0y = 0.f, a0z = 0.f, a0w = 0.f;
  float a1x = 0.f, a1y = 0.f, a1z = 0.f, a1w = 0.f;
  float a2x = 0.f, a2y = 0.f, a2z = 0.f, a2w = 0.f;
  float a3x = 0.f, a3y = 0.f, a3z = 0.f, a3w = 0.f;
  for (int base = s; base < e; base += 64) {
    int rem = e - base;
    int m = rem < 64 ? rem : 64;
    int jj = csr[base + (lane < m ? lane : m - 1)];  // coalesced, in-bounds
    int t = 0;
    for (; t + 4 <= m; t += 4) {
      int j0 = __shfl(jj, t);
      int j1 = __shfl(jj, t + 1);
      int j2 = __shfl(jj, t + 2);
      int j3 = __shfl(jj, t + 3);
      ushort4 v0 = *(const ushort4*)(Cl + (size_t)j0 * D_HID + c);
      ushort4 v1 = *(const ushort4*)(Cl + (size_t)j1 * D_HID + c);
      ushort4 v2 = *(const ushort4*)(Cl + (size_t)j2 * D_HID + c);
      ushort4 v3 = *(const ushort4*)(Cl + (size_t)j3 * D_HID + c);
      a0x += bf2f(v0.x); a0y += bf2f(v0.y); a0z += bf2f(v0.z); a0w += bf2f(v0.w);
      a1x += bf2f(v1.x); a1y += bf2f(v1.y); a1z += bf2f(v1.z); a1w += bf2f(v1.w);
      a2x += bf2f(v2.x); a2y += bf2f(v2.y); a2z += bf2f(v2.z); a2w += bf2f(v2.w);
      a3x += bf2f(v3.x); a3y += bf2f(v3.y); a3z += bf2f(v3.z); a3w += bf2f(v3.w);
    }
    for (; t < m; t++) {
      int j0 = __shfl(jj, t);
      ushort4 v = *(const ushort4*)(Cl + (size_t)j0 * D_HID + c);
      a0x += bf2f(v.x); a0y += bf2f(v.y); a0z += bf2f(v.z); a0w += bf2f(v.w);
    }
  }
  float ax = (a0x + a1x) + (a2x + a3x);
  float ay = (a0y + a1y) + (a2y + a3y);
  float az = (a0z + a1z) + (a2z + a3z);
  float aw = (a0w + a1w) + (a2w + a3w);
  float inv = 1.0f / fmaxf((float)(e - s), 1.0f);
  float h0 = fmaxf(ax * inv + bv.x + bf2f(q.x), 0.0f);
  float h1 = fmaxf(ay * inv + bv.y + bf2f(q.y), 0.0f);
  float h2 = fmaxf(az * inv + bv.z + bf2f(q.z), 0.0f);
  float h3 = fmaxf(aw * inv + bv.w + bf2f(q.w), 0.0f);
  float r0 = h0 * wl0.x + h1 * wl0.y + h2 * wl0.z + h3 * wl0.w;
  float r1 = h0 * wl1.x + h1 * wl1.y + h2 * wl1.z + h3 * wl1.w;
  float s0 = h0 * wr0.x + h1 * wr0.y + h2 * wr0.z + h3 * wr0.w;
  float s1 = h0 * wr1.x + h1 * wr1.y + h2 * wr1.z + h3 * wr1.w;
#pragma unroll
  for (int off = 32; off > 0; off >>= 1) {
    r0 += __shfl_xor(r0, off);
    r1 += __shfl_xor(r1, off);
    s0 += __shfl_xor(s0, off);
    s1 += __shfl_xor(s1, off);
  }
  if (lane == 0) rs[i] = make_float4(r0, r1, s0, s1);
}

// --------------------------- final -----------------------------------------
// out[i][j] = mean_{k in N(i)} rs[k][j] + b2[j] + rs[i][2+j]
__global__ void final_k(const float4* __restrict__ rs, const int* __restrict__ offs,
                        const int* __restrict__ csr, const float* __restrict__ b2,
                        float* __restrict__ out, int M) {
  int i = blockIdx.x * 256 + threadIdx.x;
  if (i >= M) return;
  int s = offs[i], e = offs[i + 1];
  float a0 = 0.0f, a1 = 0.0f, b0 = 0.0f, b1 = 0.0f;
  int t = s;
  for (; t + 2 <= e; t += 2) {
    float4 v0 = rs[csr[t]];
    float4 v1 = rs[csr[t + 1]];
    a0 += v0.x; a1 += v0.y;
    b0 += v1.x; b1 += v1.y;
  }
  if (t < e) { float4 v = rs[csr[t]]; a0 += v.x; a1 += v.y; }
  a0 += b0; a1 += b1;
  float inv = 1.0f / fmaxf((float)(e - s), 1.0f);
  float4 me = rs[i];
  out[2 * i + 0] = a0 * inv + b2[0] + me.z;
  out[2 * i + 1] = a1 * inv + b2[1] + me.w;
}

// ---------------------------------------------------------------------------

extern "C" void kernel_launch(void* const* d_in, const int* in_sizes, int n_in,
                              void* d_out, int out_size, void* d_ws, size_t ws_size,
                              hipStream_t stream) {
  const float* x   = (const float*)d_in[0];
  const void*  eix = d_in[1];
  const float* W1l = (const float*)d_in[2];
  const float* b1  = (const float*)d_in[3];
  const float* W1r = (const float*)d_in[4];
  const float* W2l = (const float*)d_in[5];
  const float* b2  = (const float*)d_in[6];
  const float* W2r = (const float*)d_in[7];
  float* out = (float*)d_out;

  const int M  = in_sizes[0] / D_IN;       // 50000
  const int E  = in_sizes[1] / 2;          // 250000
  const int Mp = ((M + 127) / 128) * 128;  // 50048
  const int nb = (M + 1023) / 1024;        // scan blocks (<=64)
  const int MT = Mp / 128;                 // 391 m-tiles
  const int mtPerXcd = (MT + 7) / 8;       // 49
  const int gemmBlocks = 8 * mtPerXcd * 4; // 1568 (some return early)

  // workspace layout (256B aligned slots)
  char* ws = (char*)d_ws;
  size_t off = 0;
  auto alloc = [&](size_t b) { size_t o = off; off += (b + 255) & ~(size_t)255; return o; };
  size_t oCounts = alloc((size_t)M * 4);
  size_t zeroBytes = (size_t)M * 4;        // counts
  size_t oOffs   = alloc((size_t)(M + 1) * 4);
  size_t oCursor = alloc((size_t)M * 4);
  size_t oCsr    = alloc((size_t)E * 4);
  size_t oSrc    = alloc((size_t)E * 4);
  size_t oDst    = alloc((size_t)E * 4);
  size_t oBSums  = alloc(64 * 4);
  size_t oWb     = alloc((size_t)N1 * D_IN * 2);
  size_t oCl     = alloc((size_t)Mp * D_HID * 2);  // bf16 neighbor half
  size_t oCr     = alloc((size_t)Mp * D_HID * 2);  // bf16 self half
  size_t oRs     = alloc((size_t)M * 16);
  size_t oXb     = alloc((size_t)Mp * D_IN * 2);   // bf16 x, padded
  (void)ws_size; (void)n_in; (void)out_size;

  int* counts = (int*)(ws + oCounts);
  int* offs   = (int*)(ws + oOffs);
  int* cursor = (int*)(ws + oCursor);
  int* csr    = (int*)(ws + oCsr);
  int* src32  = (int*)(ws + oSrc);
  int* dst32  = (int*)(ws + oDst);
  int* bsums  = (int*)(ws + oBSums);
  unsigned short* wb = (unsigned short*)(ws + oWb);
  unsigned short* Cl = (unsigned short*)(ws + oCl);
  unsigned short* Cr = (unsigned short*)(ws + oCr);
  float4* rs = (float4*)(ws + oRs);
  unsigned short* xb = (unsigned short*)(ws + oXb);

  hipMemsetAsync(counts, 0, zeroBytes, stream);

  int gE = (E + 255) / 256;                         // 977
  int gW = (N1 * (D_IN / 8) + 255) / 256;           // 192
  int gX = (Mp * (D_IN / 8) + 255) / 256;           // 18768
  prep_k<<<gE + gW + gX, 256, 0, stream>>>(eix, src32, dst32, counts, E,
                                           W1l, W1r, wb, x, xb, M, Mp, gE, gW);
  scanA_k<<<nb, 256, 0, stream>>>(counts, bsums, M);
  scanC_k<<<nb, 256, 0, stream>>>(counts, bsums, offs, cursor, M, E, nb);
  fill_k<<<(E + 255) / 256, 256, 0, stream>>>(src32, dst32, cursor, csr, E);

  gemm_k<<<gemmBlocks, 512, 0, stream>>>(xb, wb, Cl, Cr, MT, mtPerXcd);

  agg_l2_k<<<(M + 3) / 4, 256, 0, stream>>>(Cl, Cr, offs, csr, b1, W2l, W2r,
                                            rs, M);
  final_k<<<(M + 255) / 256, 256, 0, stream>>>(rs, offs, csr, b2, out, M);
}